// Round 4
// baseline (169.885 us; speedup 1.0000x reference)
//
#include <hip/hip_runtime.h>

#define B_ 64
#define NB_ 8
#define Q_ 32
#define T_ 256
#define D_ 256
#define NBINS 11

typedef __attribute__((ext_vector_type(8))) short bf16x8;
typedef __attribute__((ext_vector_type(4))) float f32x4;
typedef unsigned short ushort_t;
typedef unsigned int uint_t;

// ws byte offsets: fragment-ordered bf16 hi/lo of can (B-side) and hq
// (A-side), + per-outb bin partial sums.
#define CANH_OFF 0u          //  8 MB
#define CANL_OFF 8388608u    //  8 MB
#define HQH_OFF 16777216u    //  8 MB
#define HQL_OFF 25165824u    //  8 MB
#define PSUM_OFF 33554432u   //  720 KB: 512 outb x 352 floats

__device__ inline ushort_t bf16_rnd(float f) {
  uint_t u = __float_as_uint(f);
  return (ushort_t)((u + 0x8000u) >> 16);
}
__device__ inline uint_t pack2(ushort_t a, ushort_t b) {
  return (uint_t)a | ((uint_t)b << 16);
}

// 11 independent exps (R0-validated form).
__device__ inline void bins_acc(f32x4 acc, float mk, float binacc[4][NBINS]) {
  const float mus[NBINS] = {1.0f, 0.9f, 0.7f, 0.5f, 0.3f, 0.1f,
                            -0.1f, -0.3f, -0.5f, -0.7f, -0.9f};
  const float nis2[NBINS] = {-5.0e5f, -50.f, -50.f, -50.f, -50.f, -50.f,
                             -50.f, -50.f, -50.f, -50.f, -50.f};
#pragma unroll
  for (int r = 0; r < 4; r++) {
    float v0 = acc[r];
#pragma unroll
    for (int j = 0; j < NBINS; j++) {
      float d0 = v0 - mus[j];
      binacc[r][j] += mk * __expf(d0 * d0 * nis2[j]);
    }
  }
}

// ---------------------------------------------------------------------------
// split_kernel (unchanged from R3): row-norm + hi/lo bf16 split -> fragment-
// ordered ws for can (blocks 0..511) and hq (blocks 512..1023).
// ---------------------------------------------------------------------------
__global__ __launch_bounds__(256) void split_kernel(
    const float* __restrict__ can, const float* __restrict__ hq,
    uint4* __restrict__ canH, uint4* __restrict__ canL,
    uint4* __restrict__ hqH, uint4* __restrict__ hqL) {
  __shared__ __align__(16) ushort_t sm_hi[32 * 264];
  __shared__ __align__(16) ushort_t sm_lo[32 * 264];
  int blk = blockIdx.x;
  int tid = threadIdx.x;
  const float* src;
  uint4 *dH, *dL;
  int tilebase;
  if (blk < 512) {
    int b = blk >> 3, ch = blk & 7;
    src = can + ((size_t)b * T_ + ch * 32) * D_;
    dH = canH;
    dL = canL;
    tilebase = b * 16 + ch * 2;
  } else {
    int outb = blk - 512;
    src = hq + (size_t)outb * (Q_ * D_);
    dH = hqH;
    dL = hqL;
    tilebase = outb * 2;
  }

#pragma unroll
  for (int it = 0; it < 4; it++) {
    int flat = it * 2048 + tid * 8;
    int row = flat >> 8, col = flat & 255;
    const float* p = src + row * D_ + col;
    float4 x = reinterpret_cast<const float4*>(p)[0];
    float4 y = reinterpret_cast<const float4*>(p)[1];
    float s = x.x * x.x + x.y * x.y + x.z * x.z + x.w * x.w +
              y.x * y.x + y.y * y.y + y.z * y.z + y.w * y.w;
    s += __shfl_xor(s, 1);
    s += __shfl_xor(s, 2);
    s += __shfl_xor(s, 4);
    s += __shfl_xor(s, 8);
    s += __shfl_xor(s, 16);
    float inv = 1.0f / fmaxf(sqrtf(s), 1e-10f);
    float v[8] = {x.x, x.y, x.z, x.w, y.x, y.y, y.z, y.w};
    ushort_t h[8], l[8];
#pragma unroll
    for (int j = 0; j < 8; j++) {
      float sv = v[j] * inv;
      h[j] = bf16_rnd(sv);
      float hf = __uint_as_float(((uint_t)h[j]) << 16);
      l[j] = bf16_rnd(sv - hf);
    }
    uint4 ph = {pack2(h[0], h[1]), pack2(h[2], h[3]), pack2(h[4], h[5]),
                pack2(h[6], h[7])};
    uint4 pl = {pack2(l[0], l[1]), pack2(l[2], l[3]), pack2(l[4], l[5]),
                pack2(l[6], l[7])};
    *reinterpret_cast<uint4*>(&sm_hi[row * 264 + col]) = ph;
    *reinterpret_cast<uint4*>(&sm_lo[row * 264 + col]) = pl;
  }
  __syncthreads();
  int wv = tid >> 6, lane = tid & 63;
  int tl = wv >> 1, part = wv & 1;
  int lq = lane & 15, lk = lane >> 4;
  const ushort_t* smp = part ? sm_lo : sm_hi;
  uint4* dst = part ? dL : dH;
#pragma unroll
  for (int kk = 0; kk < 8; kk++) {
    const ushort_t* a = &smp[(tl * 16 + lq) * 264 + kk * 32 + lk * 8];
    dst[((size_t)(tilebase + tl) * 8 + kk) * 64 + lane] =
        *reinterpret_cast<const uint4*>(a);
  }
}

// ---------------------------------------------------------------------------
// pool_kernel v4: LDS-staged B fragments.
//   R11-R13 evidence: duration tracks vmem REQUEST bytes (~300-400 MB at a
//   stable ~7-9 TB/s service rate), not unique footprint and not occupancy.
//   The per-wave register scheme requested every can byte 16x (8 nb x 2
//   mtile). v4: grid 512=(b,nb), 4 waves = 2 mtile x 2 t-half streams; each
//   stream's B-tile staged once into LDS (reg-staging, issue-early/write-
//   late T14), both mtile waves ds_read it. vmem requests: 295 MB -> ~34 MB.
//   Per-wave MFMA/bins/reduce code identical to validated R0/R1 form.
//   LDS 64 KB (2 stream x 2 buf x 2 part x 8 KB) + partial -> 2 blocks/CU.
// XCD: i%8 = b%8, so the 8 nb-blocks of a given b share one L2.
// ---------------------------------------------------------------------------
__global__ __launch_bounds__(256, 2) void pool_kernel(
    const uint4* __restrict__ hqH, const uint4* __restrict__ hqL,
    const uint4* __restrict__ canH, const uint4* __restrict__ canL,
    const float* __restrict__ mask_can, float* __restrict__ psum) {
  // [tq][buf][part][8KB] as ushorts
  __shared__ __align__(16) ushort_t ldsB[2][2][2][4096];
  __shared__ float partial[4 * 16 * NBINS];  // 704

  int i = blockIdx.x;
  int b = i & 63;  // XCD = i%8 = b%8
  int nb = i >> 6;
  int outb = b * NB_ + nb;
  int tid = threadIdx.x;
  int wv = tid >> 6, lane = tid & 63;
  int lq = lane & 15, lk = lane >> 4;
  int mtile = wv & 1, tq = wv >> 1;  // 2 mtile x 2 t-half streams

  // ---- A fragments: straight 16B loads (pre-converted by split) ----
  bf16x8 ah[8], al[8];
  size_t abase = (size_t)(outb * 2 + mtile) * 512 + lane;
#pragma unroll
  for (int kk = 0; kk < 8; kk++) {
    ah[kk] = *reinterpret_cast<const bf16x8*>(&hqH[abase + kk * 64]);
    al[kk] = *reinterpret_cast<const bf16x8*>(&hqL[abase + kk * 64]);
  }

  // masks for this wave's 8 tiles (off the serial chain)
  float mkv[8];
#pragma unroll
  for (int ti = 0; ti < 8; ti++)
    mkv[ti] = mask_can[b * T_ + (tq * 8 + ti) * 16 + lq];

  // this wave stages part=mtile (H or L) of stream tq
  const uint4* srcP = mtile ? canL : canH;
  // LDS addressing by integer offsets (no runtime-indexed ptr arrays)
  ushort_t* sb = &ldsB[tq][0][0][0];           // stream base
  const int BUFSTRIDE = 2 * 4096;              // ushorts per buf
  int myPart = mtile * 4096;

  size_t tbase = (size_t)(b * 16 + tq * 8) * 512 + lane;  // uint4 units

  // prologue: stage tile 0 into buf 0
  {
    uint4 stg[8];
#pragma unroll
    for (int kk = 0; kk < 8; kk++) stg[kk] = srcP[tbase + kk * 64];
#pragma unroll
    for (int kk = 0; kk < 8; kk++)
      *reinterpret_cast<uint4*>(&sb[myPart + kk * 512 + lane * 8]) = stg[kk];
  }
  __syncthreads();

  float binacc[4][NBINS];
#pragma unroll
  for (int r = 0; r < 4; r++)
#pragma unroll
    for (int j = 0; j < NBINS; j++) binacc[r][j] = 0.0f;

  f32x4 accPrev;
  float mkPrev = 0.0f;
  int bufoff = 0;

  for (int ti = 0; ti < 8; ti++) {
    // issue next tile's global loads early (complete under compute)
    uint4 stg[8];
    if (ti < 7) {
#pragma unroll
      for (int kk = 0; kk < 8; kk++)
        stg[kk] = srcP[tbase + (size_t)(ti + 1) * 512 + kk * 64];
    }
    // consume staged tile from LDS: per-kk ds_read + 3-MFMA hi/lo chain
    f32x4 acc = {0.f, 0.f, 0.f, 0.f};
#pragma unroll
    for (int kk = 0; kk < 8; kk++) {
      bf16x8 bh = *reinterpret_cast<const bf16x8*>(
          &sb[bufoff + 0 + kk * 512 + lane * 8]);
      bf16x8 bl = *reinterpret_cast<const bf16x8*>(
          &sb[bufoff + 4096 + kk * 512 + lane * 8]);
      acc = __builtin_amdgcn_mfma_f32_16x16x32_bf16(ah[kk], bh, acc, 0, 0, 0);
      acc = __builtin_amdgcn_mfma_f32_16x16x32_bf16(al[kk], bh, acc, 0, 0, 0);
      acc = __builtin_amdgcn_mfma_f32_16x16x32_bf16(ah[kk], bl, acc, 0, 0, 0);
    }
    // deferred bins of previous tile overlap the ds/MFMA of this one
    if (ti > 0) bins_acc(accPrev, mkPrev, binacc);
    accPrev = acc;
    mkPrev = mkv[ti];
    // write-late: staged data lands in the other buffer before the barrier
    if (ti < 7) {
      int ob = bufoff ^ BUFSTRIDE;
#pragma unroll
      for (int kk = 0; kk < 8; kk++)
        *reinterpret_cast<uint4*>(&sb[ob + myPart + kk * 512 + lane * 8]) =
            stg[kk];
    }
    __syncthreads();
    bufoff ^= BUFSTRIDE;
  }
  bins_acc(accPrev, mkPrev, binacc);  // last tile

  // ---- reduce over the 16 t-cols (lq) held by this wave ----
#pragma unroll
  for (int r = 0; r < 4; r++)
#pragma unroll
    for (int j = 0; j < NBINS; j++) {
      float v = binacc[r][j];
      v += __shfl_xor(v, 1);
      v += __shfl_xor(v, 2);
      v += __shfl_xor(v, 4);
      v += __shfl_xor(v, 8);
      binacc[r][j] = v;
    }
  if (lq == 0) {
#pragma unroll
    for (int r = 0; r < 4; r++)
#pragma unroll
      for (int j = 0; j < NBINS; j++)
        partial[(wv * 16 + lk * 4 + r) * NBINS + j] = binacc[r][j];
  }
  __syncthreads();

  // combine the two tq halves -> 352 complete bin sums for outb
  for (int idx = tid; idx < Q_ * NBINS; idx += 256) {
    int q = idx / NBINS;
    int j = idx - q * NBINS;
    int m = q >> 4, r16 = q & 15;
    float s = partial[((0 + m) * 16 + r16) * NBINS + j] +
              partial[((2 + m) * 16 + r16) * NBINS + j];
    psum[(size_t)outb * (Q_ * NBINS) + idx] = s;
  }
}

// ---------------------------------------------------------------------------
// finish_kernel (R3 form, psum now single-segment): grid 64, one block per b.
// Waves 0-1: qproj (2 dims/thread, unroll-8). Waves 2-3: log-pool staging.
// Then pooled, 8 scores, masked softmax, tanh-dense, direct out[b] store.
// ---------------------------------------------------------------------------
__global__ __launch_bounds__(256) void finish_kernel(
    const float* __restrict__ psum, const float* __restrict__ word_atten,
    const float* __restrict__ mask_hq, const float* __restrict__ rep,
    const float* __restrict__ rep_cur, const float* __restrict__ mask_session,
    const float* __restrict__ W_dense, const float* __restrict__ b_dense,
    const float* __restrict__ W_att, const float* __restrict__ b_att,
    float* __restrict__ out) {
  __shared__ float qproj[256];
  __shared__ float lp_sm[NB_ * Q_ * NBINS];  // 2816
  __shared__ float pooled_sm[NB_ * NBINS];   // 88
  __shared__ float scores_sm[NB_];

  int b = blockIdx.x;
  int tid = threadIdx.x;
  int wv = tid >> 6, lane = tid & 63;

  if (wv < 2) {
    const float* rc = rep_cur + b * D_;
    float a0 = b_att[tid], a1 = b_att[tid + 128];
#pragma unroll 8
    for (int k = 0; k < D_; k++) {
      float r = rc[k];
      a0 += r * W_att[k * D_ + tid];
      a1 += r * W_att[k * D_ + tid + 128];
    }
    qproj[tid] = a0;
    qproj[tid + 128] = a1;
  } else {
    int t2 = tid - 128;
    for (int idx = t2; idx < NB_ * Q_ * NBINS; idx += 128) {
      int nn = idx / (Q_ * NBINS);
      int rem = idx - nn * (Q_ * NBINS);
      int q = rem / NBINS;
      int outb = b * NB_ + nn;
      float s = psum[(size_t)outb * (Q_ * NBINS) + rem];
      float wa = word_atten[outb * Q_ + q] * mask_hq[outb * Q_ + q];
      lp_sm[idx] = logf(fmaxf(s, 1e-10f)) * 0.01f * wa;
    }
  }
  __syncthreads();

  if (tid < NB_ * NBINS) {
    int nn = tid / NBINS, j = tid - nn * NBINS;
    float s = 0.f;
#pragma unroll
    for (int q = 0; q < Q_; q++) s += lp_sm[(nn * Q_ + q) * NBINS + j];
    pooled_sm[tid] = s;
  }

  for (int nn = wv; nn < NB_; nn += 4) {
    const float* rp = rep + ((size_t)b * NB_ + nn) * D_;
    float4 r4 = reinterpret_cast<const float4*>(rp)[lane];
    float4 q4 = *reinterpret_cast<float4*>(&qproj[lane * 4]);
    float s = r4.x * q4.x + r4.y * q4.y + r4.z * q4.z + r4.w * q4.w;
#pragma unroll
    for (int off = 32; off > 0; off >>= 1) s += __shfl_down(s, off);
    if (lane == 0) scores_sm[nn] = s * 0.0625f;  // 1/sqrt(256)
  }
  __syncthreads();

  if (tid == 0) {
    float sc[NB_];
    float mx = -1e30f;
    for (int nn = 0; nn < NB_; nn++) {
      float s = (mask_session[b * NB_ + nn] > 0.f) ? scores_sm[nn] : -1e9f;
      sc[nn] = s;
      mx = fmaxf(mx, s);
    }
    float den = 0.f;
    for (int nn = 0; nn < NB_; nn++) {
      sc[nn] = __expf(sc[nn] - mx);
      den += sc[nn];
    }
    float invd = 1.0f / den;
    float res = 0.f;
    for (int nn = 0; nn < NB_; nn++) {
      float ms = mask_session[b * NB_ + nn];
      float pw = b_dense[0];
#pragma unroll
      for (int j = 0; j < NBINS; j++)
        pw += pooled_sm[nn * NBINS + j] * ms * W_dense[j];
      res += tanhf(pw) * sc[nn] * invd;
    }
    out[b] = res;
  }
}

// ---------------------------------------------------------------------------
// 3 dispatches: split (1024 blk), pool (512 blk), finish (64 blk).
// ws: canH/L + hqH/L (32 MB) + psum (720 KB).
// ---------------------------------------------------------------------------
extern "C" void kernel_launch(void* const* d_in, const int* in_sizes, int n_in,
                              void* d_out, int out_size, void* d_ws,
                              size_t ws_size, hipStream_t stream) {
  const float* word_atten = (const float*)d_in[0];
  const float* hq = (const float*)d_in[1];
  const float* can = (const float*)d_in[2];
  const float* rep = (const float*)d_in[3];
  const float* rep_cur = (const float*)d_in[4];
  const float* mask_hq = (const float*)d_in[5];
  const float* mask_can = (const float*)d_in[6];
  const float* mask_session = (const float*)d_in[7];
  const float* W_dense = (const float*)d_in[8];
  const float* b_dense = (const float*)d_in[9];
  const float* W_att = (const float*)d_in[10];
  const float* b_att = (const float*)d_in[11];
  float* out = (float*)d_out;

  char* ws = (char*)d_ws;
  uint4* canH = (uint4*)(ws + CANH_OFF);
  uint4* canL = (uint4*)(ws + CANL_OFF);
  uint4* hqH = (uint4*)(ws + HQH_OFF);
  uint4* hqL = (uint4*)(ws + HQL_OFF);
  float* psum = (float*)(ws + PSUM_OFF);

  hipLaunchKernelGGL(split_kernel, dim3(1024), dim3(256), 0, stream, can, hq,
                     canH, canL, hqH, hqL);
  hipLaunchKernelGGL(pool_kernel, dim3(512), dim3(256), 0, stream, hqH, hqL,
                     canH, canL, mask_can, psum);
  hipLaunchKernelGGL(finish_kernel, dim3(B_), dim3(256), 0, stream, psum,
                     word_atten, mask_hq, rep, rep_cur, mask_session, W_dense,
                     b_dense, W_att, b_att, out);
}

// Round 5
// 131.525 us; speedup vs baseline: 1.2917x; 1.2917x over previous
//
#include <hip/hip_runtime.h>

#define B_ 64
#define NB_ 8
#define Q_ 32
#define T_ 256
#define D_ 256
#define NBINS 11

typedef __attribute__((ext_vector_type(8))) short bf16x8;
typedef __attribute__((ext_vector_type(4))) float f32x4;
typedef unsigned short ushort_t;
typedef unsigned int uint_t;

// ws byte offsets: fragment-ordered bf16 hi/lo split of can. Nothing else.
#define CANH_OFF 0u
#define CANL_OFF 8388608u

__device__ inline ushort_t bf16_rnd(float f) {
  uint_t u = __float_as_uint(f);
  return (ushort_t)((u + 0x8000u) >> 16);
}
__device__ inline uint_t pack2(ushort_t a, ushort_t b) {
  return (uint_t)a | ((uint_t)b << 16);
}

// async global->LDS, 16B per lane, zero staging registers.
// dest must be wave-uniform base (lane i lands at base + i*16); our fragment
// layout is exactly that (linear 64 x 16B). Source is per-lane.
__device__ inline void gld_lds16(const void* g, void* l) {
  __builtin_amdgcn_global_load_lds(
      (const __attribute__((address_space(1))) void*)g,
      (__attribute__((address_space(3))) void*)l, 16, 0, 0);
}

// ---------------------------------------------------------------------------
// split_kernel: EXACT R0 (126.6us-validated) version. can row-norm + hi/lo
// bf16 split -> fragment-ordered ws. Grid 512 = (b 64, 32-row chunk 8).
// Also zeroes out[64] for pool's atomicAdd accumulation.
// ---------------------------------------------------------------------------
__global__ __launch_bounds__(256) void split_kernel(
    const float* __restrict__ can, uint4* __restrict__ canH,
    uint4* __restrict__ canL, float* __restrict__ out) {
  __shared__ __align__(16) ushort_t sm_hi[32 * 264];
  __shared__ __align__(16) ushort_t sm_lo[32 * 264];
  int blk = blockIdx.x;
  int tid = threadIdx.x;
  if (tid == 0 && blk < B_) out[blk] = 0.0f;
  int b = blk >> 3, ch = blk & 7;
  const float* src = can + ((size_t)b * T_ + ch * 32) * D_;
  int tilebase = b * 16 + ch * 2;

#pragma unroll
  for (int it = 0; it < 4; it++) {
    int flat = it * 2048 + tid * 8;
    int row = flat >> 8, col = flat & 255;
    const float* p = src + row * D_ + col;
    float4 x = reinterpret_cast<const float4*>(p)[0];
    float4 y = reinterpret_cast<const float4*>(p)[1];
    float s = x.x * x.x + x.y * x.y + x.z * x.z + x.w * x.w +
              y.x * y.x + y.y * y.y + y.z * y.z + y.w * y.w;
    // 32 consecutive threads cover one 256-col row
    s += __shfl_xor(s, 1);
    s += __shfl_xor(s, 2);
    s += __shfl_xor(s, 4);
    s += __shfl_xor(s, 8);
    s += __shfl_xor(s, 16);
    float inv = 1.0f / fmaxf(sqrtf(s), 1e-10f);
    float v[8] = {x.x, x.y, x.z, x.w, y.x, y.y, y.z, y.w};
    ushort_t h[8], l[8];
#pragma unroll
    for (int j = 0; j < 8; j++) {
      float sv = v[j] * inv;
      h[j] = bf16_rnd(sv);
      float hf = __uint_as_float(((uint_t)h[j]) << 16);
      l[j] = bf16_rnd(sv - hf);
    }
    uint4 ph = {pack2(h[0], h[1]), pack2(h[2], h[3]), pack2(h[4], h[5]),
                pack2(h[6], h[7])};
    uint4 pl = {pack2(l[0], l[1]), pack2(l[2], l[3]), pack2(l[4], l[5]),
                pack2(l[6], l[7])};
    *reinterpret_cast<uint4*>(&sm_hi[row * 264 + col]) = ph;
    *reinterpret_cast<uint4*>(&sm_lo[row * 264 + col]) = pl;
  }
  __syncthreads();
  int wv = tid >> 6, lane = tid & 63;
  int tl = wv >> 1, part = wv & 1;  // tile-local 0/1, hi/lo part
  int lq = lane & 15, lk = lane >> 4;
  const ushort_t* smp = part ? sm_lo : sm_hi;
  uint4* dst = part ? canL : canH;
#pragma unroll
  for (int kk = 0; kk < 8; kk++) {
    const ushort_t* a = &smp[(tl * 16 + lq) * 264 + kk * 32 + lk * 8];
    dst[((size_t)(tilebase + tl) * 8 + kk) * 64 + lane] =
        *reinterpret_cast<const uint4*>(a);
  }
}

// ---------------------------------------------------------------------------
// pool_kernel v5: R0 body (register A-split, deferred bins, shfl+LDS reduce,
// self-contained epilogue) with ONE change: B fragments now arrive via
// global_load_lds (async HBM/L2 -> LDS, no staging VGPRs), double-buffered
// per t-stream, shared by both mtile waves.
//   R11-R14 evidence: pool dur tracks register behavior (VGPR 84 -> 44.5us,
//   60 -> 65, 96+spill -> 66); at 84 VGPRs the compiler demotes the bh/bl
//   prefetch to just-in-time loads, exposing ~300cy L2 latency per kk-group.
//   global_load_lds removes the 64-VGPR B-staging entirely (Common-mistake
//   #1) and halves B requests (mtile waves share the LDS tile).
// Per-iter: issue gld(t+1) -> bins(t-1) (~700cy VALU covers load flight) ->
// ds_read_b128 + 3-MFMA chain (t) -> barrier (vmcnt drain ~= free).
// LDS: 64KB tiles + 5.3KB epilogue = 70KB -> 2 blocks/CU at (256,2).
// XCD swizzle: blockIdx%8 = b%8 -> can[b] fragments stay in one L2.
// ---------------------------------------------------------------------------
__global__ __launch_bounds__(256, 2) void pool_kernel(
    const float* __restrict__ hq, const uint4* __restrict__ canH,
    const uint4* __restrict__ canL, const float* __restrict__ mask_can,
    const float* __restrict__ word_atten, const float* __restrict__ mask_hq,
    const float* __restrict__ rep, const float* __restrict__ rep_cur,
    const float* __restrict__ mask_session, const float* __restrict__ W_dense,
    const float* __restrict__ b_dense, const float* __restrict__ W_att,
    const float* __restrict__ b_att, float* __restrict__ out) {
  // B-tile buffers: [tq][buf][part][4096 ushorts(=8KB)] = 64 KB
  __shared__ __align__(16) ushort_t ldsB[2][2][2][4096];
  // epilogue: partial[704] | lp[352] | qproj[256] | scores[8] | pooled[11]
  __shared__ float smbuf[1331];
  float* partial = smbuf;            // 704
  float* lp_sm = smbuf + 704;        // 352
  float* qproj = smbuf + 1056;       // 256
  float* scores_sm = smbuf + 1312;   // 8
  float* pooled_sm = smbuf + 1320;   // 11

  const float mus[NBINS] = {1.0f, 0.9f, 0.7f, 0.5f, 0.3f, 0.1f,
                            -0.1f, -0.3f, -0.5f, -0.7f, -0.9f};
  const float nis2[NBINS] = {-5.0e5f, -50.f, -50.f, -50.f, -50.f, -50.f,
                             -50.f, -50.f, -50.f, -50.f, -50.f};

  int i = blockIdx.x;
  int b = i & 63;  // XCD = i%8 = b%8
  int nb = i >> 6;
  int outb = b * NB_ + nb;
  int tid = threadIdx.x;
  int wv = tid >> 6, lane = tid & 63;
  int lq = lane & 15, lk = lane >> 4;
  int mtile = wv & 1, tq = wv >> 1;

  // ---- A fragments: register norm + hi/lo split (R0-validated) ----
  const float* arow =
      hq + (size_t)outb * (Q_ * D_) + (size_t)(mtile * 16 + lq) * D_;
  float sumsq = 0.f;
#pragma unroll
  for (int kk = 0; kk < 8; kk++) {
    const float* p = arow + kk * 32 + lk * 8;
    float4 x = reinterpret_cast<const float4*>(p)[0];
    float4 y = reinterpret_cast<const float4*>(p)[1];
    sumsq += x.x * x.x + x.y * x.y + x.z * x.z + x.w * x.w +
             y.x * y.x + y.y * y.y + y.z * y.z + y.w * y.w;
  }
  sumsq += __shfl_xor(sumsq, 16);
  sumsq += __shfl_xor(sumsq, 32);
  float ainv = 1.0f / fmaxf(sqrtf(sumsq), 1e-10f);

  bf16x8 ah[8], al[8];
#pragma unroll
  for (int kk = 0; kk < 8; kk++) {
    const float* p = arow + kk * 32 + lk * 8;  // L1-hot reload
    float4 x = reinterpret_cast<const float4*>(p)[0];
    float4 y = reinterpret_cast<const float4*>(p)[1];
    float v[8] = {x.x, x.y, x.z, x.w, y.x, y.y, y.z, y.w};
    union { bf16x8 v8; ushort_t u[8]; } H, L;
#pragma unroll
    for (int j = 0; j < 8; j++) {
      float s = v[j] * ainv;
      ushort_t h = bf16_rnd(s);
      float hf = __uint_as_float(((uint_t)h) << 16);
      H.u[j] = h;
      L.u[j] = bf16_rnd(s - hf);
    }
    ah[kk] = H.v8;
    al[kk] = L.v8;
  }

  // ---- B-tile async pipeline ----
  // wave (mtile, tq) stages part=mtile (H or L) of stream tq's tiles.
  const uint4* srcP = mtile ? canL : canH;
  ushort_t* sb = &ldsB[tq][0][0][0];   // stream base (wave-uniform)
  const int BUF = 2 * 4096;            // ushorts per buffer
  int myPart = mtile * 4096;
  size_t tbase = (size_t)(b * 16 + tq * 8) * 512 + lane;  // uint4 units

  // prologue: stage tile 0 into buf 0 (dest wave-uniform; lane spreads x16B)
#pragma unroll
  for (int kk = 0; kk < 8; kk++)
    gld_lds16(&srcP[tbase + kk * 64], &sb[myPart + kk * 512]);
  __syncthreads();  // drains vmcnt -> tile 0 resident

  float binacc[4][NBINS];
#pragma unroll
  for (int r = 0; r < 4; r++)
#pragma unroll
    for (int j = 0; j < NBINS; j++) binacc[r][j] = 0.0f;

  f32x4 accPrev;
  float mkPrev = 0.0f;
  int bufoff = 0;

  for (int ti = 0; ti < 8; ti++) {
    // issue next tile's async loads into the other buffer (no regs consumed)
    if (ti < 7) {
      int ob = bufoff ^ BUF;
#pragma unroll
      for (int kk = 0; kk < 8; kk++)
        gld_lds16(&srcP[tbase + (size_t)(ti + 1) * 512 + kk * 64],
                  &sb[ob + myPart + kk * 512]);
    }
    // deferred bins of previous tile: ~700cy VALU covering the load flight
    if (ti > 0) bins_acc_body: {
      ;
    }
    if (ti > 0) {
#pragma unroll
      for (int r = 0; r < 4; r++) {
        float v0 = accPrev[r];
#pragma unroll
        for (int j = 0; j < NBINS; j++) {
          float d0 = v0 - mus[j];
          binacc[r][j] += mkPrev * __expf(d0 * d0 * nis2[j]);
        }
      }
    }
    // consume current tile from LDS: ds_read_b128 + 3-MFMA hi/lo chain
    f32x4 acc = {0.f, 0.f, 0.f, 0.f};
#pragma unroll
    for (int kk = 0; kk < 8; kk++) {
      bf16x8 bh = *reinterpret_cast<const bf16x8*>(
          &sb[bufoff + 0 + kk * 512 + lane * 8]);
      bf16x8 bl = *reinterpret_cast<const bf16x8*>(
          &sb[bufoff + 4096 + kk * 512 + lane * 8]);
      acc = __builtin_amdgcn_mfma_f32_16x16x32_bf16(ah[kk], bh, acc, 0, 0, 0);
      acc = __builtin_amdgcn_mfma_f32_16x16x32_bf16(al[kk], bh, acc, 0, 0, 0);
      acc = __builtin_amdgcn_mfma_f32_16x16x32_bf16(ah[kk], bl, acc, 0, 0, 0);
    }
    accPrev = acc;
    mkPrev = mask_can[b * T_ + (tq * 8 + ti) * 16 + lq];
    // barrier: syncs consumers + drains next-tile vmcnt (loads had the whole
    // bins+MFMA phase to complete -> drain ~= free)
    __syncthreads();
    bufoff ^= BUF;
  }
#pragma unroll
  for (int r = 0; r < 4; r++) {  // bins of last tile
    float v0 = accPrev[r];
#pragma unroll
    for (int j = 0; j < NBINS; j++) {
      float d0 = v0 - mus[j];
      binacc[r][j] += mkPrev * __expf(d0 * d0 * nis2[j]);
    }
  }

  // ---- reduce over the 16 t-cols (lq) held by this wave ----
#pragma unroll
  for (int r = 0; r < 4; r++)
#pragma unroll
    for (int j = 0; j < NBINS; j++) {
      float v = binacc[r][j];
      v += __shfl_xor(v, 1);
      v += __shfl_xor(v, 2);
      v += __shfl_xor(v, 4);
      v += __shfl_xor(v, 8);
      binacc[r][j] = v;
    }
  if (lq == 0) {
#pragma unroll
    for (int r = 0; r < 4; r++)
#pragma unroll
      for (int j = 0; j < NBINS; j++)
        partial[(wv * 16 + lk * 4 + r) * NBINS + j] = binacc[r][j];
  }
  __syncthreads();

  // ---- in-block epilogue (EXACT R0 form) ----
  // (a) combine tq halves + log-pool * word_atten * mask_hq -> lp_sm.
  for (int idx = tid; idx < Q_ * NBINS; idx += 256) {
    int q = idx / NBINS;
    int j = idx - q * NBINS;
    int m = q >> 4, r16 = q & 15;
    float sum = partial[(m * 16 + r16) * NBINS + j] +
                partial[((2 + m) * 16 + r16) * NBINS + j];
    float wa = word_atten[outb * Q_ + q] * mask_hq[outb * Q_ + q];
    lp_sm[idx] = logf(fmaxf(sum, 1e-10f)) * 0.01f * wa;
  }

  // (b) W_att projection (input-only; duplicated across the 8 nb-blocks of b)
  {
    const float* rc = rep_cur + b * D_;
    float acc2 = b_att[tid];
    for (int k = 0; k < D_; k++) acc2 += rc[k] * W_att[k * D_ + tid];
    qproj[tid] = acc2;
  }
  __syncthreads();

  // (c) pooled[j] = sum_q lp (this block's nb only)
  if (tid < NBINS) {
    float s = 0.f;
#pragma unroll
    for (int q = 0; q < Q_; q++) s += lp_sm[q * NBINS + tid];
    pooled_sm[tid] = s;
  }

  // (d) all 8 attention scores (each wave does 2)
  for (int nn = wv; nn < NB_; nn += 4) {
    const float* rp = rep + ((size_t)b * NB_ + nn) * D_;
    float4 r4 = reinterpret_cast<const float4*>(rp)[lane];
    float4 q4 = *reinterpret_cast<float4*>(&qproj[lane * 4]);
    float s = r4.x * q4.x + r4.y * q4.y + r4.z * q4.z + r4.w * q4.w;
#pragma unroll
    for (int off = 32; off > 0; off >>= 1) s += __shfl_down(s, off);
    if (lane == 0) scores_sm[nn] = s * 0.0625f;  // 1/sqrt(256)
  }
  __syncthreads();

  // (e) masked softmax (local, deterministic) + this nb's contribution
  if (tid == 0) {
    float sc[NB_];
    float mx = -1e30f;
    for (int nn = 0; nn < NB_; nn++) {
      float s = (mask_session[b * NB_ + nn] > 0.f) ? scores_sm[nn] : -1e9f;
      sc[nn] = s;
      mx = fmaxf(mx, s);
    }
    float den = 0.f;
    for (int nn = 0; nn < NB_; nn++) {
      sc[nn] = __expf(sc[nn] - mx);
      den += sc[nn];
    }
    float ms = mask_session[b * NB_ + nb];
    float pw = b_dense[0];
#pragma unroll
    for (int j = 0; j < NBINS; j++) pw += pooled_sm[j] * ms * W_dense[j];
    float res = tanhf(pw) * (sc[nb] / den);
    atomicAdd(&out[b], res);  // 512 total atomics; out zeroed by split_kernel
  }
}

// ---------------------------------------------------------------------------
// ws: canH/canL only (16.8 MB). 2 dispatches total; no psum, no fences.
// ---------------------------------------------------------------------------
extern "C" void kernel_launch(void* const* d_in, const int* in_sizes, int n_in,
                              void* d_out, int out_size, void* d_ws,
                              size_t ws_size, hipStream_t stream) {
  const float* word_atten = (const float*)d_in[0];
  const float* hq = (const float*)d_in[1];
  const float* can = (const float*)d_in[2];
  const float* rep = (const float*)d_in[3];
  const float* rep_cur = (const float*)d_in[4];
  const float* mask_hq = (const float*)d_in[5];
  const float* mask_can = (const float*)d_in[6];
  const float* mask_session = (const float*)d_in[7];
  const float* W_dense = (const float*)d_in[8];
  const float* b_dense = (const float*)d_in[9];
  const float* W_att = (const float*)d_in[10];
  const float* b_att = (const float*)d_in[11];
  float* out = (float*)d_out;

  char* ws = (char*)d_ws;
  uint4* canH = (uint4*)(ws + CANH_OFF);
  uint4* canL = (uint4*)(ws + CANL_OFF);

  hipLaunchKernelGGL(split_kernel, dim3(512), dim3(256), 0, stream, can, canH,
                     canL, out);
  hipLaunchKernelGGL(pool_kernel, dim3(B_ * NB_), dim3(256), 0, stream, hq,
                     canH, canL, mask_can, word_atten, mask_hq, rep, rep_cur,
                     mask_session, W_dense, b_dense, W_att, b_att, out);
}

// Round 6
// 125.806 us; speedup vs baseline: 1.3504x; 1.0455x over previous
//
#include <hip/hip_runtime.h>

#define B_ 64
#define NB_ 8
#define Q_ 32
#define T_ 256
#define D_ 256
#define NBINS 11

typedef __attribute__((ext_vector_type(8))) short bf16x8;
typedef __attribute__((ext_vector_type(4))) float f32x4;
typedef unsigned short ushort_t;
typedef unsigned int uint_t;

// ws byte offsets: fragment-ordered bf16 hi/lo split of can. Nothing else.
#define CANH_OFF 0u
#define CANL_OFF 8388608u

__device__ inline ushort_t bf16_rnd(float f) {
  uint_t u = __float_as_uint(f);
  return (ushort_t)((u + 0x8000u) >> 16);
}
__device__ inline uint_t pack2(ushort_t a, ushort_t b) {
  return (uint_t)a | ((uint_t)b << 16);
}

// ---------------------------------------------------------------------------
// split_kernel: R0-validated body. ONE change vs R0 (the XCD-locality fix):
// block decode is now b = blk&63, ch = blk>>6, so split block (b,ch) lands
// on XCD blk%8 = b%8 -- the SAME XCD pool's (b,nb) blocks (XCD = b%8) read
// from. R0's decode (b=blk>>3, ch=blk&7) put chunk ch on XCD ch, scattering
// each b's fragments across all 8 XCDs; pool's FETCH_SIZE (~16.6 MB = exactly
// canH+canL, R1-measured) showed the fragments were re-fetched from HBM
// because 7/8 of reads were cross-XCD (per-XCD L2s are not coherent/shared).
// Now each XCD holds its 8 b's fragments (2 MB, fits 4 MB L2) dirty in L2
// and pool re-reads them as L2 hits. Write pattern per block is unchanged;
// out-zeroing: blk<64 is now (ch=0, b=blk) -- still each b exactly once.
// ---------------------------------------------------------------------------
__global__ __launch_bounds__(256) void split_kernel(
    const float* __restrict__ can, uint4* __restrict__ canH,
    uint4* __restrict__ canL, float* __restrict__ out) {
  __shared__ __align__(16) ushort_t sm_hi[32 * 264];
  __shared__ __align__(16) ushort_t sm_lo[32 * 264];
  int blk = blockIdx.x;
  int tid = threadIdx.x;
  if (tid == 0 && blk < B_) out[blk] = 0.0f;
  int b = blk & 63, ch = blk >> 6;  // XCD = blk%8 = b%8 (matches pool)
  const float* src = can + ((size_t)b * T_ + ch * 32) * D_;
  int tilebase = b * 16 + ch * 2;

#pragma unroll
  for (int it = 0; it < 4; it++) {
    int flat = it * 2048 + tid * 8;
    int row = flat >> 8, col = flat & 255;
    const float* p = src + row * D_ + col;
    float4 x = reinterpret_cast<const float4*>(p)[0];
    float4 y = reinterpret_cast<const float4*>(p)[1];
    float s = x.x * x.x + x.y * x.y + x.z * x.z + x.w * x.w +
              y.x * y.x + y.y * y.y + y.z * y.z + y.w * y.w;
    // 32 consecutive threads cover one 256-col row
    s += __shfl_xor(s, 1);
    s += __shfl_xor(s, 2);
    s += __shfl_xor(s, 4);
    s += __shfl_xor(s, 8);
    s += __shfl_xor(s, 16);
    float inv = 1.0f / fmaxf(sqrtf(s), 1e-10f);
    float v[8] = {x.x, x.y, x.z, x.w, y.x, y.y, y.z, y.w};
    ushort_t h[8], l[8];
#pragma unroll
    for (int j = 0; j < 8; j++) {
      float sv = v[j] * inv;
      h[j] = bf16_rnd(sv);
      float hf = __uint_as_float(((uint_t)h[j]) << 16);
      l[j] = bf16_rnd(sv - hf);
    }
    uint4 ph = {pack2(h[0], h[1]), pack2(h[2], h[3]), pack2(h[4], h[5]),
                pack2(h[6], h[7])};
    uint4 pl = {pack2(l[0], l[1]), pack2(l[2], l[3]), pack2(l[4], l[5]),
                pack2(l[6], l[7])};
    *reinterpret_cast<uint4*>(&sm_hi[row * 264 + col]) = ph;
    *reinterpret_cast<uint4*>(&sm_lo[row * 264 + col]) = pl;
  }
  __syncthreads();
  int wv = tid >> 6, lane = tid & 63;
  int tl = wv >> 1, part = wv & 1;  // tile-local 0/1, hi/lo part
  int lq = lane & 15, lk = lane >> 4;
  const ushort_t* smp = part ? sm_lo : sm_hi;
  uint4* dst = part ? canL : canH;
#pragma unroll
  for (int kk = 0; kk < 8; kk++) {
    const ushort_t* a = &smp[(tl * 16 + lq) * 264 + kk * 32 + lk * 8];
    dst[((size_t)(tilebase + tl) * 8 + kk) * 64 + lane] =
        *reinterpret_cast<const uint4*>(a);
  }
}

// ---------------------------------------------------------------------------
// pool_kernel: EXACT R0 (126.6us-validated) body -- register A-split,
// barrier-free deferred-bins 3-MFMA pipeline, shfl+LDS reduce, self-
// contained epilogue, 512 atomics. R15 evidence: pool duration (~45us) was
// invariant to per-block work, occupancy, and staging scheme -- it is the
// serial cross-XCD fragment-read latency chain, fixed by split's new block
// mapping (see split comment), not by anything in this kernel.
// XCD swizzle: blockIdx%8 = b%8 -> can[b] fragments stay in one L2.
// ---------------------------------------------------------------------------
__global__ __launch_bounds__(256, 2) void pool_kernel(
    const float* __restrict__ hq, const uint4* __restrict__ canH,
    const uint4* __restrict__ canL, const float* __restrict__ mask_can,
    const float* __restrict__ word_atten, const float* __restrict__ mask_hq,
    const float* __restrict__ rep, const float* __restrict__ rep_cur,
    const float* __restrict__ mask_session, const float* __restrict__ W_dense,
    const float* __restrict__ b_dense, const float* __restrict__ W_att,
    const float* __restrict__ b_att, float* __restrict__ out) {
  // LDS: partial[704] | lp[352] | qproj[256] | scores[8] | pooled[11]
  __shared__ float smbuf[1331];
  float* partial = smbuf;            // 704
  float* lp_sm = smbuf + 704;        // 352
  float* qproj = smbuf + 1056;       // 256
  float* scores_sm = smbuf + 1312;   // 8
  float* pooled_sm = smbuf + 1320;   // 11

  const float mus[NBINS] = {1.0f, 0.9f, 0.7f, 0.5f, 0.3f, 0.1f,
                            -0.1f, -0.3f, -0.5f, -0.7f, -0.9f};
  const float nis2[NBINS] = {-5.0e5f, -50.f, -50.f, -50.f, -50.f, -50.f,
                             -50.f, -50.f, -50.f, -50.f, -50.f};

  int i = blockIdx.x;
  int b = i & 63;  // XCD = i%8 = b%8
  int nb = i >> 6;
  int outb = b * NB_ + nb;
  int tid = threadIdx.x;
  int wv = tid >> 6, lane = tid & 63;
  int lq = lane & 15, lk = lane >> 4;
  int mtile = wv & 1, tq = wv >> 1;

  // ---- A fragments: register norm + hi/lo split (R6/R8-validated) ----
  const float* arow =
      hq + (size_t)outb * (Q_ * D_) + (size_t)(mtile * 16 + lq) * D_;
  float sumsq = 0.f;
#pragma unroll
  for (int kk = 0; kk < 8; kk++) {
    const float* p = arow + kk * 32 + lk * 8;
    float4 x = reinterpret_cast<const float4*>(p)[0];
    float4 y = reinterpret_cast<const float4*>(p)[1];
    sumsq += x.x * x.x + x.y * x.y + x.z * x.z + x.w * x.w +
             y.x * y.x + y.y * y.y + y.z * y.z + y.w * y.w;
  }
  sumsq += __shfl_xor(sumsq, 16);
  sumsq += __shfl_xor(sumsq, 32);
  float ainv = 1.0f / fmaxf(sqrtf(sumsq), 1e-10f);

  bf16x8 ah[8], al[8];
#pragma unroll
  for (int kk = 0; kk < 8; kk++) {
    const float* p = arow + kk * 32 + lk * 8;  // L1-hot reload
    float4 x = reinterpret_cast<const float4*>(p)[0];
    float4 y = reinterpret_cast<const float4*>(p)[1];
    float v[8] = {x.x, x.y, x.z, x.w, y.x, y.y, y.z, y.w};
    union { bf16x8 v8; ushort_t u[8]; } H, L;
#pragma unroll
    for (int j = 0; j < 8; j++) {
      float s = v[j] * ainv;
      ushort_t h = bf16_rnd(s);
      float hf = __uint_as_float(((uint_t)h) << 16);
      H.u[j] = h;
      L.u[j] = bf16_rnd(s - hf);
    }
    ah[kk] = H.v8;
    al[kk] = L.v8;
  }

  float binacc[4][NBINS];
#pragma unroll
  for (int r = 0; r < 4; r++)
#pragma unroll
    for (int j = 0; j < NBINS; j++) binacc[r][j] = 0.0f;

  f32x4 accPrev;
  float mkPrev = 0.0f;

  {  // tile 0
    int tt = tq * 8;
    size_t bbase = (size_t)(b * 16 + tt) * 8 * 64 + lane;
    f32x4 acc = {0.f, 0.f, 0.f, 0.f};
#pragma unroll
    for (int kk = 0; kk < 8; kk++) {
      bf16x8 bh = *reinterpret_cast<const bf16x8*>(&canH[bbase + kk * 64]);
      bf16x8 bl = *reinterpret_cast<const bf16x8*>(&canL[bbase + kk * 64]);
      acc = __builtin_amdgcn_mfma_f32_16x16x32_bf16(ah[kk], bh, acc, 0, 0, 0);
      acc = __builtin_amdgcn_mfma_f32_16x16x32_bf16(al[kk], bh, acc, 0, 0, 0);
      acc = __builtin_amdgcn_mfma_f32_16x16x32_bf16(ah[kk], bl, acc, 0, 0, 0);
    }
    accPrev = acc;
    mkPrev = mask_can[b * T_ + tt * 16 + lq];
  }

  for (int ti = 1; ti < 8; ti++) {  // load(ti) issued before bins(ti-1)
    int tt = tq * 8 + ti;
    size_t bbase = (size_t)(b * 16 + tt) * 8 * 64 + lane;
    bf16x8 bh[8], bl[8];
#pragma unroll
    for (int kk = 0; kk < 8; kk++) {
      bh[kk] = *reinterpret_cast<const bf16x8*>(&canH[bbase + kk * 64]);
      bl[kk] = *reinterpret_cast<const bf16x8*>(&canL[bbase + kk * 64]);
    }
    // C/D: col(t)=lane&15, row(q)=(lane>>4)*4+reg  [R4-validated]
#pragma unroll
    for (int r = 0; r < 4; r++) {
      float v0 = accPrev[r];
#pragma unroll
      for (int j = 0; j < NBINS; j++) {
        float d0 = v0 - mus[j];
        binacc[r][j] += mkPrev * __expf(d0 * d0 * nis2[j]);
      }
    }
    f32x4 acc = {0.f, 0.f, 0.f, 0.f};
#pragma unroll
    for (int kk = 0; kk < 8; kk++) {
      acc = __builtin_amdgcn_mfma_f32_16x16x32_bf16(ah[kk], bh[kk], acc, 0, 0, 0);
      acc = __builtin_amdgcn_mfma_f32_16x16x32_bf16(al[kk], bh[kk], acc, 0, 0, 0);
      acc = __builtin_amdgcn_mfma_f32_16x16x32_bf16(ah[kk], bl[kk], acc, 0, 0, 0);
    }
    accPrev = acc;
    mkPrev = mask_can[b * T_ + tt * 16 + lq];
  }
#pragma unroll
  for (int r = 0; r < 4; r++) {  // bins of last tile
    float v0 = accPrev[r];
#pragma unroll
    for (int j = 0; j < NBINS; j++) {
      float d0 = v0 - mus[j];
      binacc[r][j] += mkPrev * __expf(d0 * d0 * nis2[j]);
    }
  }

  // ---- reduce over the 16 t-cols (lq) held by this wave ----
#pragma unroll
  for (int r = 0; r < 4; r++)
#pragma unroll
    for (int j = 0; j < NBINS; j++) {
      float v = binacc[r][j];
      v += __shfl_xor(v, 1);
      v += __shfl_xor(v, 2);
      v += __shfl_xor(v, 4);
      v += __shfl_xor(v, 8);
      binacc[r][j] = v;
    }
  if (lq == 0) {
#pragma unroll
    for (int r = 0; r < 4; r++)
#pragma unroll
      for (int j = 0; j < NBINS; j++)
        partial[(wv * 16 + lk * 4 + r) * NBINS + j] = binacc[r][j];
  }
  __syncthreads();

  // ---- in-block epilogue (no global round-trip) ----
  // (a) combine tq halves + log-pool * word_atten * mask_hq -> lp_sm.
  //     STRIDED over 352 items (R3 lesson).
  for (int idx = tid; idx < Q_ * NBINS; idx += 256) {
    int q = idx / NBINS;
    int j = idx - q * NBINS;
    int m = q >> 4, r16 = q & 15;
    float sum = partial[(m * 16 + r16) * NBINS + j] +
                partial[((2 + m) * 16 + r16) * NBINS + j];
    float wa = word_atten[outb * Q_ + q] * mask_hq[outb * Q_ + q];
    lp_sm[idx] = logf(fmaxf(sum, 1e-10f)) * 0.01f * wa;
  }

  // (b) W_att projection (input-only; duplicated across the 8 nb-blocks of b)
  {
    const float* rc = rep_cur + b * D_;
    float acc2 = b_att[tid];
    for (int k = 0; k < D_; k++) acc2 += rc[k] * W_att[k * D_ + tid];
    qproj[tid] = acc2;
  }
  __syncthreads();

  // (c) pooled[j] = sum_q lp (this block's nb only)
  if (tid < NBINS) {
    float s = 0.f;
#pragma unroll
    for (int q = 0; q < Q_; q++) s += lp_sm[q * NBINS + tid];
    pooled_sm[tid] = s;
  }

  // (d) all 8 attention scores (each wave does 2)
  for (int nn = wv; nn < NB_; nn += 4) {
    const float* rp = rep + ((size_t)b * NB_ + nn) * D_;
    float4 r4 = reinterpret_cast<const float4*>(rp)[lane];
    float4 q4 = *reinterpret_cast<float4*>(&qproj[lane * 4]);
    float s = r4.x * q4.x + r4.y * q4.y + r4.z * q4.z + r4.w * q4.w;
#pragma unroll
    for (int off = 32; off > 0; off >>= 1) s += __shfl_down(s, off);
    if (lane == 0) scores_sm[nn] = s * 0.0625f;  // 1/sqrt(256)
  }
  __syncthreads();

  // (e) masked softmax (local, deterministic) + this nb's contribution
  if (tid == 0) {
    float sc[NB_];
    float mx = -1e30f;
    for (int nn = 0; nn < NB_; nn++) {
      float s = (mask_session[b * NB_ + nn] > 0.f) ? scores_sm[nn] : -1e9f;
      sc[nn] = s;
      mx = fmaxf(mx, s);
    }
    float den = 0.f;
    for (int nn = 0; nn < NB_; nn++) {
      sc[nn] = __expf(sc[nn] - mx);
      den += sc[nn];
    }
    float ms = mask_session[b * NB_ + nb];
    float pw = b_dense[0];
#pragma unroll
    for (int j = 0; j < NBINS; j++) pw += pooled_sm[j] * ms * W_dense[j];
    float res = tanhf(pw) * (sc[nb] / den);
    atomicAdd(&out[b], res);  // 512 total atomics; out zeroed by split_kernel
  }
}

// ---------------------------------------------------------------------------
// ws: canH/canL only (16.8 MB). 2 dispatches total; no psum, no fences.
// ---------------------------------------------------------------------------
extern "C" void kernel_launch(void* const* d_in, const int* in_sizes, int n_in,
                              void* d_out, int out_size, void* d_ws,
                              size_t ws_size, hipStream_t stream) {
  const float* word_atten = (const float*)d_in[0];
  const float* hq = (const float*)d_in[1];
  const float* can = (const float*)d_in[2];
  const float* rep = (const float*)d_in[3];
  const float* rep_cur = (const float*)d_in[4];
  const float* mask_hq = (const float*)d_in[5];
  const float* mask_can = (const float*)d_in[6];
  const float* mask_session = (const float*)d_in[7];
  const float* W_dense = (const float*)d_in[8];
  const float* b_dense = (const float*)d_in[9];
  const float* W_att = (const float*)d_in[10];
  const float* b_att = (const float*)d_in[11];
  float* out = (float*)d_out;

  char* ws = (char*)d_ws;
  uint4* canH = (uint4*)(ws + CANH_OFF);
  uint4* canL = (uint4*)(ws + CANL_OFF);

  hipLaunchKernelGGL(split_kernel, dim3(512), dim3(256), 0, stream, can, canH,
                     canL, out);
  hipLaunchKernelGGL(pool_kernel, dim3(B_ * NB_), dim3(256), 0, stream, hq,
                     canH, canL, mask_can, word_atten, mask_hq, rep, rep_cur,
                     mask_session, W_dense, b_dense, W_att, b_att, out);
}